// Round 7
// baseline (126.378 us; speedup 1.0000x reference)
//
#include <hip/hip_runtime.h>

// ColorReducer: per pixel argmin_k ||p - palette[k]||^2, output palette color,
// planar (B,3,H,W) layout.
//
// CORRECTNESS CONTRACT (verified R4/R5/R6, absmax=0.0): ref=np fp32,
//   dot = fma(b,cb, fma(g,cg, rn(r*cr)))        ascending scalar FMA chain
//   pp  = ((r*r+g*g)+b*b), cc = ((cr*cr+cg*cg)+cb*cb)   fwd, no FMA
//   d   = (pp - 2*dot) + cc   left-to-right; 2*dot exact
//   argmin first-index strict <
// Packed f32 (v_pk_*) is IEEE-identical per half; pixel-pairing preserves
// bit-exactness. DO NOT change the arithmetic op sequence.
//
// R7 = R6 + MEASUREMENT: main kernel launched TWICE (idempotent -> correct;
// serial same-stream -> graph-safe). dur_delta vs R6 (97.5us) = one kernel's
// true cost, disambiguating "kernel ~40us" vs "harness floor ~90us".

typedef float f2 __attribute__((ext_vector_type(2)));

constexpr int HW   = 512 * 512;   // pixels per plane (2^18)
constexpr int NCOL = 64;

__global__ __launch_bounds__(64)
void coef_kernel(const float* __restrict__ pal, f2* __restrict__ coef) {
  const int k = threadIdx.x;
  if (k < NCOL) {
    const float cr = pal[k * 3 + 0];
    const float cg = pal[k * 3 + 1];
    const float cb = pal[k * 3 + 2];
    // cc: forward sequential, no FMA (contract)
    const float cc = __fadd_rn(__fadd_rn(__fmul_rn(cr, cr), __fmul_rn(cg, cg)),
                               __fmul_rn(cb, cb));
    coef[k * 4 + 0] = (f2){cr, cr};
    coef[k * 4 + 1] = (f2){cg, cg};
    coef[k * 4 + 2] = (f2){cb, cb};
    coef[k * 4 + 3] = (f2){cc, cc};
  }
}

__global__ __launch_bounds__(256)
void color_reduce_kernel(const float* __restrict__ x,
                         const float* __restrict__ pal,
                         const f2* __restrict__ coef,
                         float* __restrict__ out,
                         int npix4) {
  __shared__ float4 praw[NCOL];   // (r,g,b,0) for the final gather only
  const int tid = threadIdx.x;
  if (tid < NCOL) {
    praw[tid] = make_float4(pal[tid * 3 + 0], pal[tid * 3 + 1],
                            pal[tid * 3 + 2], 0.f);
  }
  __syncthreads();

  const int i4 = blockIdx.x * blockDim.x + tid;   // group of 4 consecutive pixels
  if (i4 >= npix4) return;
  const int pix = i4 << 2;
  const int bi  = pix >> 18;        // / HW
  const int j   = pix & (HW - 1);   // % HW
  const size_t base = (size_t)bi * (3 * HW) + j;

  const float4 R = *(const float4*)(x + base);
  const float4 G = *(const float4*)(x + base + HW);
  const float4 B = *(const float4*)(x + base + 2 * HW);

  // pp: forward sequential, no FMA (contract)
  float pp[4];
  const float rr[4] = {R.x, R.y, R.z, R.w};
  const float gg[4] = {G.x, G.y, G.z, G.w};
  const float bv[4] = {B.x, B.y, B.z, B.w};
#pragma unroll
  for (int p = 0; p < 4; ++p)
    pp[p] = __fadd_rn(__fadd_rn(__fmul_rn(rr[p], rr[p]), __fmul_rn(gg[p], gg[p])),
                      __fmul_rn(bv[p], bv[p]));

  const f2 r01 = {R.x, R.y}, r23 = {R.z, R.w};
  const f2 g01 = {G.x, G.y}, g23 = {G.z, G.w};
  const f2 b01 = {B.x, B.y}, b23 = {B.z, B.w};
  const f2 pp01 = {pp[0], pp[1]}, pp23 = {pp[2], pp[3]};

  float m0 = 3.4e38f, m1 = 3.4e38f, m2 = 3.4e38f, m3 = 3.4e38f;
  int id0 = 0, id1 = 0, id2 = 0, id3 = 0;

#pragma unroll 8
  for (int k = 0; k < NCOL; ++k) {
    // Uniform loads -> s_load_dwordx2 pairs (SGPR); pk ops consume directly.
    const f2 crv = coef[k * 4 + 0];
    const f2 cgv = coef[k * 4 + 1];
    const f2 cbv = coef[k * 4 + 2];
    const f2 ccv = coef[k * 4 + 3];

    // Exact numpy chain, packed over pixel pairs (per-half IEEE rn).
    f2 dot01 = __builtin_elementwise_fma(
        b01, cbv, __builtin_elementwise_fma(g01, cgv, r01 * crv));
    f2 dot23 = __builtin_elementwise_fma(
        b23, cbv, __builtin_elementwise_fma(g23, cgv, r23 * crv));
    const f2 e01 = (pp01 - (dot01 + dot01)) + ccv;   // no muls -> no contraction
    const f2 e23 = (pp23 - (dot23 + dot23)) + ccv;

    bool lt;
    lt = e01.x < m0; m0 = lt ? e01.x : m0; id0 = lt ? k : id0;
    lt = e01.y < m1; m1 = lt ? e01.y : m1; id1 = lt ? k : id1;
    lt = e23.x < m2; m2 = lt ? e23.x : m2; id2 = lt ? k : id2;
    lt = e23.y < m3; m3 = lt ? e23.y : m3; id3 = lt ? k : id3;
  }

  const float4 c0 = praw[id0], c1 = praw[id1], c2 = praw[id2], c3 = praw[id3];
  *(float4*)(out + base)          = make_float4(c0.x, c1.x, c2.x, c3.x);
  *(float4*)(out + base + HW)     = make_float4(c0.y, c1.y, c2.y, c3.y);
  *(float4*)(out + base + 2 * HW) = make_float4(c0.z, c1.z, c2.z, c3.z);
}

extern "C" void kernel_launch(void* const* d_in, const int* in_sizes, int n_in,
                              void* d_out, int out_size, void* d_ws, size_t ws_size,
                              hipStream_t stream) {
  const float* x   = (const float*)d_in[0];
  const float* pal = (const float*)d_in[1];
  float* out = (float*)d_out;
  f2* coef = (f2*)d_ws;   // 64 colors x 4 splat pairs = 2 KiB

  hipLaunchKernelGGL(coef_kernel, dim3(1), dim3(64), 0, stream, pal, coef);

  const int npix  = in_sizes[0] / 3;   // B*H*W = 2,097,152
  const int npix4 = npix / 4;          // 524,288 threads -> 8192 waves, 8/SIMD
  const int block = 256;
  const int grid  = (npix4 + block - 1) / block;
  // Launched TWICE on purpose (R7 measurement; idempotent, graph-safe).
  hipLaunchKernelGGL(color_reduce_kernel, dim3(grid), dim3(block), 0, stream,
                     x, pal, coef, out, npix4);
  hipLaunchKernelGGL(color_reduce_kernel, dim3(grid), dim3(block), 0, stream,
                     x, pal, coef, out, npix4);
}

// Round 8
// 117.043 us; speedup vs baseline: 1.0798x; 1.0798x over previous
//
#include <hip/hip_runtime.h>

// ColorReducer: per pixel argmin_k ||p - palette[k]||^2, output palette color,
// planar (B,3,H,W) layout.
//
// CORRECTNESS CONTRACT (verified R4/R5/R6/R7, absmax=0.0): ref=np fp32,
//   dot = fma(b,cb, fma(g,cg, rn(r*cr)))        ascending scalar FMA chain
//   pp  = ((r*r+g*g)+b*b), cc = ((cr*cr+cg*cg)+cb*cb)   fwd, no FMA
//   d   = (pp - 2*dot) + cc   left-to-right; 2*dot exact
//   argmin first-index strict <
// R8 transform (bit-exact): precompute c2=2c. x2 is exact, so
//   s = fma(b,2cb, fma(g,2cg, rn(r*2cr))) == 2*dot with identical roundings
//   d = (pp - s) + cc   — same bits as the contract. 10 pk instr/k, was 12.
// Packed f32 (v_pk_*) is IEEE-identical per half. DO NOT alter op sequence.
//
// R8 MEASUREMENT: kernel body repeated rep_count=2 times inside ONE dispatch
// (opaque rep_off=0 defeats CSE; idempotent; graph-safe) so the dispatch
// (~55us) exceeds the 43us fill cutoff and finally shows its counters in
// top-5. R9 reverts to rep_count=1.

typedef float f2 __attribute__((ext_vector_type(2)));

constexpr int HW   = 512 * 512;   // pixels per plane (2^18)
constexpr int NCOL = 64;

__global__ __launch_bounds__(64)
void coef_kernel(const float* __restrict__ pal, f2* __restrict__ coef) {
  const int k = threadIdx.x;
  if (k < NCOL) {
    const float cr = pal[k * 3 + 0];
    const float cg = pal[k * 3 + 1];
    const float cb = pal[k * 3 + 2];
    // cc: forward sequential, no FMA (contract)
    const float cc = __fadd_rn(__fadd_rn(__fmul_rn(cr, cr), __fmul_rn(cg, cg)),
                               __fmul_rn(cb, cb));
    coef[k * 4 + 0] = (f2){cr + cr, cr + cr};   // 2c exact
    coef[k * 4 + 1] = (f2){cg + cg, cg + cg};
    coef[k * 4 + 2] = (f2){cb + cb, cb + cb};
    coef[k * 4 + 3] = (f2){cc, cc};
  }
}

__global__ __launch_bounds__(256)
void color_reduce_kernel(const float* __restrict__ x,
                         const float* __restrict__ pal,
                         const f2* __restrict__ coef,
                         float* __restrict__ out,
                         int npix4, int rep_count, long rep_off) {
  __shared__ float4 praw[NCOL];   // (r,g,b,0) for the final gather only
  const int tid = threadIdx.x;
  if (tid < NCOL) {
    praw[tid] = make_float4(pal[tid * 3 + 0], pal[tid * 3 + 1],
                            pal[tid * 3 + 2], 0.f);
  }
  __syncthreads();

  const int i4 = blockIdx.x * blockDim.x + tid;   // group of 4 consecutive pixels
  if (i4 >= npix4) return;
  const int pix = i4 << 2;
  const int bi  = pix >> 18;        // / HW
  const int j   = pix & (HW - 1);   // % HW
  const size_t base0 = (size_t)bi * (3 * HW) + j;

  for (int rep = 0; rep < rep_count; ++rep) {
    // rep_off is 0 at runtime but opaque to the compiler -> body re-executes.
    const size_t base = base0 + (size_t)rep * (size_t)rep_off;

    const float4 R = *(const float4*)(x + base);
    const float4 G = *(const float4*)(x + base + HW);
    const float4 B = *(const float4*)(x + base + 2 * HW);

    // pp: forward sequential, no FMA (contract)
    float pp[4];
    const float rr[4] = {R.x, R.y, R.z, R.w};
    const float gg[4] = {G.x, G.y, G.z, G.w};
    const float bv[4] = {B.x, B.y, B.z, B.w};
#pragma unroll
    for (int p = 0; p < 4; ++p)
      pp[p] = __fadd_rn(__fadd_rn(__fmul_rn(rr[p], rr[p]), __fmul_rn(gg[p], gg[p])),
                        __fmul_rn(bv[p], bv[p]));

    const f2 r01 = {R.x, R.y}, r23 = {R.z, R.w};
    const f2 g01 = {G.x, G.y}, g23 = {G.z, G.w};
    const f2 b01 = {B.x, B.y}, b23 = {B.z, B.w};
    const f2 pp01 = {pp[0], pp[1]}, pp23 = {pp[2], pp[3]};

    float m0 = 3.4e38f, m1 = 3.4e38f, m2 = 3.4e38f, m3 = 3.4e38f;
    int id0 = 0, id1 = 0, id2 = 0, id3 = 0;

#pragma unroll 8
    for (int k = 0; k < NCOL; ++k) {
      const f2 c2r = coef[k * 4 + 0];
      const f2 c2g = coef[k * 4 + 1];
      const f2 c2b = coef[k * 4 + 2];
      const f2 ccv = coef[k * 4 + 3];

      // s = 2*dot, bit-exact (x2 commutes with every rounding).
      const f2 s01 = __builtin_elementwise_fma(
          b01, c2b, __builtin_elementwise_fma(g01, c2g, r01 * c2r));
      const f2 s23 = __builtin_elementwise_fma(
          b23, c2b, __builtin_elementwise_fma(g23, c2g, r23 * c2r));
      const f2 e01 = (pp01 - s01) + ccv;   // adds/subs only -> no contraction
      const f2 e23 = (pp23 - s23) + ccv;

      bool lt;
      lt = e01.x < m0; m0 = lt ? e01.x : m0; id0 = lt ? k : id0;
      lt = e01.y < m1; m1 = lt ? e01.y : m1; id1 = lt ? k : id1;
      lt = e23.x < m2; m2 = lt ? e23.x : m2; id2 = lt ? k : id2;
      lt = e23.y < m3; m3 = lt ? e23.y : m3; id3 = lt ? k : id3;
    }

    const float4 c0 = praw[id0], c1 = praw[id1], c2 = praw[id2], c3 = praw[id3];
    float* o = out + base;
    *(float4*)(o)          = make_float4(c0.x, c1.x, c2.x, c3.x);
    *(float4*)(o + HW)     = make_float4(c0.y, c1.y, c2.y, c3.y);
    *(float4*)(o + 2 * HW) = make_float4(c0.z, c1.z, c2.z, c3.z);
  }
}

extern "C" void kernel_launch(void* const* d_in, const int* in_sizes, int n_in,
                              void* d_out, int out_size, void* d_ws, size_t ws_size,
                              hipStream_t stream) {
  const float* x   = (const float*)d_in[0];
  const float* pal = (const float*)d_in[1];
  float* out = (float*)d_out;
  f2* coef = (f2*)d_ws;   // 64 colors x 4 splat pairs = 2 KiB

  hipLaunchKernelGGL(coef_kernel, dim3(1), dim3(64), 0, stream, pal, coef);

  const int npix  = in_sizes[0] / 3;   // B*H*W = 2,097,152
  const int npix4 = npix / 4;          // 524,288 threads -> 8192 waves, 8/SIMD
  const int block = 256;
  const int grid  = (npix4 + block - 1) / block;
  // rep_count=2, rep_off=0: one ~55us dispatch -> visible in top-5 counters.
  hipLaunchKernelGGL(color_reduce_kernel, dim3(grid), dim3(block), 0, stream,
                     x, pal, coef, out, npix4, 2, 0L);
}

// Round 9
// 97.205 us; speedup vs baseline: 1.3001x; 1.2041x over previous
//
#include <hip/hip_runtime.h>

// ColorReducer: per pixel argmin_k ||p - palette[k]||^2, output palette color,
// planar (B,3,H,W) layout.
//
// CORRECTNESS CONTRACT (verified R4-R8, absmax=0.0): ref=np fp32,
//   dot = fma(b,cb, fma(g,cg, rn(r*cr)))        ascending scalar FMA chain
//   pp  = ((r*r+g*g)+b*b), cc = ((cr*cr+cg*cg)+cb*cb)   fwd, no FMA
//   d   = (pp - 2*dot) + cc   left-to-right; 2*dot exact
//   argmin first-index strict <
// Bit-exact transform (R8): coefs store c2=2c; s = fma(b,2cb, fma(g,2cg,
// rn(r*2cr))) == 2*dot with identical roundings; d = (pp - s) + cc.
// DO NOT alter the arithmetic op sequence.
//
// R9 perf change (from R8 counters: VALUBusy 70%, 2x modeled VALU cycles):
// packed f32 is THROUGHPUT-NEUTRAL on CDNA4 (wave64 v_pk_*_f32 = 4 cyc on
// SIMD-32; fp32 peak = 32 FMA/cyc/SIMD), and VOP3P's 64-bit coef operands
// cost SGPR->VGPR moves (~8/k) in every R4-R8 variant. So: pure SCALAR fp32
// arithmetic with 32-bit SGPR coefficient operands consumed directly by
// v_fma_f32/v_add_f32 (1 SGPR operand/instr is legal, zero movs).
// 8 VALU/px/k -> 32 instr/k/thread -> ~64 cyc/k/wave, ~14-17us kernel.

constexpr int HW   = 512 * 512;   // pixels per plane (2^18)
constexpr int NCOL = 64;

__global__ __launch_bounds__(64)
void coef_kernel(const float* __restrict__ pal, float* __restrict__ coef) {
  const int k = threadIdx.x;
  if (k < NCOL) {
    const float cr = pal[k * 3 + 0];
    const float cg = pal[k * 3 + 1];
    const float cb = pal[k * 3 + 2];
    // cc: forward sequential, no FMA (contract)
    const float cc = __fadd_rn(__fadd_rn(__fmul_rn(cr, cr), __fmul_rn(cg, cg)),
                               __fmul_rn(cb, cb));
    coef[k * 4 + 0] = cr + cr;   // 2c exact
    coef[k * 4 + 1] = cg + cg;
    coef[k * 4 + 2] = cb + cb;
    coef[k * 4 + 3] = cc;
  }
}

__global__ __launch_bounds__(256)
void color_reduce_kernel(const float* __restrict__ x,
                         const float* __restrict__ pal,
                         const float* __restrict__ coef,
                         float* __restrict__ out,
                         int npix4) {
  __shared__ float4 praw[NCOL];   // (r,g,b,0) for the final gather only
  const int tid = threadIdx.x;
  if (tid < NCOL) {
    praw[tid] = make_float4(pal[tid * 3 + 0], pal[tid * 3 + 1],
                            pal[tid * 3 + 2], 0.f);
  }
  __syncthreads();

  const int i4 = blockIdx.x * blockDim.x + tid;   // group of 4 consecutive pixels
  if (i4 >= npix4) return;
  const int pix = i4 << 2;
  const int bi  = pix >> 18;        // / HW
  const int j   = pix & (HW - 1);   // % HW
  const size_t base = (size_t)bi * (3 * HW) + j;

  const float4 R = *(const float4*)(x + base);
  const float4 G = *(const float4*)(x + base + HW);
  const float4 B = *(const float4*)(x + base + 2 * HW);

  const float rr[4] = {R.x, R.y, R.z, R.w};
  const float gg[4] = {G.x, G.y, G.z, G.w};
  const float bb[4] = {B.x, B.y, B.z, B.w};

  // pp: forward sequential, no FMA (contract)
  float pp[4];
#pragma unroll
  for (int p = 0; p < 4; ++p)
    pp[p] = __fadd_rn(__fadd_rn(__fmul_rn(rr[p], rr[p]), __fmul_rn(gg[p], gg[p])),
                      __fmul_rn(bb[p], bb[p]));

  float m[4] = {3.4e38f, 3.4e38f, 3.4e38f, 3.4e38f};
  int idx[4] = {0, 0, 0, 0};

#pragma unroll 8
  for (int k = 0; k < NCOL; ++k) {
    // Scalar uniform loads -> 32-bit SGPRs; VALU ops consume them directly.
    const float c2r = coef[k * 4 + 0];
    const float c2g = coef[k * 4 + 1];
    const float c2b = coef[k * 4 + 2];
    const float cc  = coef[k * 4 + 3];

#pragma unroll
    for (int p = 0; p < 4; ++p) {
      // s = 2*dot, bit-exact (x2 commutes with every rounding).
      const float s = __fmaf_rn(bb[p], c2b,
                        __fmaf_rn(gg[p], c2g,
                          __fmul_rn(rr[p], c2r)));
      const float e = __fadd_rn(__fsub_rn(pp[p], s), cc);
      const bool lt = e < m[p];                 // strict < => first-index
      m[p]   = lt ? e : m[p];
      idx[p] = lt ? k : idx[p];
    }
  }

  const float4 c0 = praw[idx[0]], c1 = praw[idx[1]],
               c2 = praw[idx[2]], c3 = praw[idx[3]];
  *(float4*)(out + base)          = make_float4(c0.x, c1.x, c2.x, c3.x);
  *(float4*)(out + base + HW)     = make_float4(c0.y, c1.y, c2.y, c3.y);
  *(float4*)(out + base + 2 * HW) = make_float4(c0.z, c1.z, c2.z, c3.z);
}

extern "C" void kernel_launch(void* const* d_in, const int* in_sizes, int n_in,
                              void* d_out, int out_size, void* d_ws, size_t ws_size,
                              hipStream_t stream) {
  const float* x   = (const float*)d_in[0];
  const float* pal = (const float*)d_in[1];
  float* out = (float*)d_out;
  float* coef = (float*)d_ws;   // 64 colors x 4 floats = 1 KiB

  hipLaunchKernelGGL(coef_kernel, dim3(1), dim3(64), 0, stream, pal, coef);

  const int npix  = in_sizes[0] / 3;   // B*H*W = 2,097,152
  const int npix4 = npix / 4;          // 524,288 threads -> 8192 waves
  const int block = 256;
  const int grid  = (npix4 + block - 1) / block;
  hipLaunchKernelGGL(color_reduce_kernel, dim3(grid), dim3(block), 0, stream,
                     x, pal, coef, out, npix4);
}